// Round 1
// baseline (406.509 us; speedup 1.0000x reference)
//
#include <hip/hip_runtime.h>

// ImageReconstruction: fused unfold -> soft-VQ (softmax over 256 codes) ->
// weighted reconstruct -> fold, plus choice penalty scalar.
//
// Layout facts:
//   img:  (64,1,512,512) fp32;  patch (b,ht,wt), element d = kh*8+kw
//   blk:  (256,8,8) fp32;       code k, element d = kh*8+kw   (same d order)
//   out:  16777216 recon floats + 1 penalty float
//
// Math: softmax(-35*sqerr) == softmax(35*(2*ab - b2))   (a2 shift cancels)
//       penalty = 1 - sum_{n,k} relu(2*w - 1) / N       (exact identity)
// Sparse GEMM2: skip codes with w < TAU; error <= 256*TAU*max|code| = 2.6e-4.

namespace {
constexpr int   HALF   = 128;                 // codes per LDS half
constexpr float BETA_C = 35.0f;
constexpr float TAU    = 1e-6f;
constexpr int   NPATCH = 64 * 64 * 64;        // 262144
constexpr size_t IMG_ELEMS = (size_t)64 * 512 * 512;
}

template <int H>
__device__ __forceinline__ void stage_codes(float* sC, const float* __restrict__ blk,
                                            int tid) {
  // 8192 floats; read blk[(H*128+kl)*64 + d] == blk[H*8192 + f], fully coalesced.
  // Write swizzled: col = kl ^ ((d&15)<<1)  (keeps even/odd pair adjacent for b64
  // reads; staging writes land <=4-way conflicted instead of 64-way).
#pragma unroll 8
  for (int i = 0; i < 32; ++i) {
    int f = i * 256 + tid;
    int kl = f >> 6;
    int d = f & 63;
    float v = blk[H * 8192 + f];
    sC[d * HALF + (kl ^ ((d & 15) << 1))] = v;
  }
}

template <int H>
__device__ __forceinline__ void gemm_half(float (&acc)[16][4], float (&b2acc)[4],
                                          const float* sC, const float* sP,
                                          int lane, int wave) {
  const float* prBase = &sP[wave * 16];
#pragma unroll 4
  for (int d = 0; d < 64; ++d) {
    // lane's two codes this half: k_local = 2*lane, 2*lane+1 (swizzle-matched)
    const float2 c2 = *reinterpret_cast<const float2*>(
        &sC[d * HALF + 2 * (lane ^ (d & 15))]);
    b2acc[2 * H]     += c2.x * c2.x;
    b2acc[2 * H + 1] += c2.y * c2.y;
    const float* pr = prBase + d * 64;
#pragma unroll
    for (int pg = 0; pg < 4; ++pg) {
      const float4 pa = *reinterpret_cast<const float4*>(pr + pg * 4);  // broadcast
      acc[pg * 4 + 0][2 * H]     += pa.x * c2.x;
      acc[pg * 4 + 0][2 * H + 1] += pa.x * c2.y;
      acc[pg * 4 + 1][2 * H]     += pa.y * c2.x;
      acc[pg * 4 + 1][2 * H + 1] += pa.y * c2.y;
      acc[pg * 4 + 2][2 * H]     += pa.z * c2.x;
      acc[pg * 4 + 2][2 * H + 1] += pa.z * c2.y;
      acc[pg * 4 + 3][2 * H]     += pa.w * c2.x;
      acc[pg * 4 + 3][2 * H + 1] += pa.w * c2.y;
    }
  }
}

__global__ __launch_bounds__(256, 3) void recon_kernel(
    const float* __restrict__ img, const float* __restrict__ blk,
    float* __restrict__ out, float* __restrict__ penAcc) {
  __shared__ float sC[64 * HALF];   // 32 KB, codesT half, swizzled
  __shared__ float sP[64 * 64];     // 16 KB, patches [d][wt]

  const int tid = threadIdx.x;
  const int lane = tid & 63;
  const int wave = tid >> 6;
  const int b = blockIdx.x >> 6;
  const int ht = blockIdx.x & 63;

  // ---- stage patches: 8 image rows x 512 floats, coalesced float4 ----
  const float* imgBase = img + (size_t)b * (512 * 512) + (size_t)(ht * 8) * 512;
#pragma unroll
  for (int i = 0; i < 4; ++i) {
    int f4 = i * 256 + tid;           // float4 index, 128 per image row
    int row = f4 >> 7;
    int c4 = f4 & 127;
    float4 v = reinterpret_cast<const float4*>(imgBase + row * 512)[c4];
    int col = c4 * 4;
    int wt = col >> 3;
    int dbase = row * 8 + (col & 7);  // col&7 in {0,4}; 4 elems same wt
    sP[(dbase + 0) * 64 + wt] = v.x;
    sP[(dbase + 1) * 64 + wt] = v.y;
    sP[(dbase + 2) * 64 + wt] = v.z;
    sP[(dbase + 3) * 64 + wt] = v.w;
  }
  stage_codes<0>(sC, blk, tid);
  __syncthreads();

  float acc[16][4];
  float b2acc[4] = {0.f, 0.f, 0.f, 0.f};
#pragma unroll
  for (int p = 0; p < 16; ++p)
#pragma unroll
    for (int j = 0; j < 4; ++j) acc[p][j] = 0.f;

  gemm_half<0>(acc, b2acc, sC, sP, lane, wave);
  __syncthreads();
  stage_codes<1>(sC, blk, tid);
  __syncthreads();
  gemm_half<1>(acc, b2acc, sC, sP, lane, wave);

  // lane's 4 global codes: {2*lane, 2*lane+1, 128+2*lane, 128+2*lane+1}
  float pen = 0.f;
  const int wtBase = wave * 16;
  const int kh = lane >> 3, kw = lane & 7;
  float* outRowBase =
      out + (size_t)b * (512 * 512) + (size_t)(ht * 8 + kh) * 512 + kw;

  for (int p = 0; p < 16; ++p) {
    float l0 = BETA_C * (2.f * acc[p][0] - b2acc[0]);
    float l1 = BETA_C * (2.f * acc[p][1] - b2acc[1]);
    float l2 = BETA_C * (2.f * acc[p][2] - b2acc[2]);
    float l3 = BETA_C * (2.f * acc[p][3] - b2acc[3]);
    float m = fmaxf(fmaxf(l0, l1), fmaxf(l2, l3));
#pragma unroll
    for (int off = 32; off >= 1; off >>= 1)
      m = fmaxf(m, __shfl_xor(m, off, 64));
    float e0 = __expf(l0 - m), e1 = __expf(l1 - m);
    float e2 = __expf(l2 - m), e3 = __expf(l3 - m);
    float s = (e0 + e1) + (e2 + e3);
#pragma unroll
    for (int off = 32; off >= 1; off >>= 1) s += __shfl_xor(s, off, 64);
    float inv = 1.0f / s;
    float w0 = e0 * inv, w1 = e1 * inv, w2 = e2 * inv, w3 = e3 * inv;
    pen += fmaxf(2.f * w0 - 1.f, 0.f) + fmaxf(2.f * w1 - 1.f, 0.f) +
           fmaxf(2.f * w2 - 1.f, 0.f) + fmaxf(2.f * w3 - 1.f, 0.f);

    bool flag = (w0 > TAU) || (w1 > TAU) || (w2 > TAU) || (w3 > TAU);
    unsigned long long mask = __ballot(flag ? 1 : 0);
    float r = 0.f;
    while (mask) {                      // typically 1-2 iterations (one-hot)
      int L = __builtin_ctzll(mask);
      mask &= (mask - 1);
      float q0 = __shfl(w0, L, 64);
      float q1 = __shfl(w1, L, 64);
      float q2 = __shfl(w2, L, 64);
      float q3 = __shfl(w3, L, 64);
      const float* cb = blk + (2 * L) * 64 + lane;  // L2-hot codebook, coalesced
      if (q0 > TAU) r = fmaf(q0, cb[0], r);
      if (q1 > TAU) r = fmaf(q1, cb[64], r);
      if (q2 > TAU) r = fmaf(q2, cb[HALF * 64], r);
      if (q3 > TAU) r = fmaf(q3, cb[HALF * 64 + 64], r);
    }
    outRowBase[(wtBase + p) * 8] = r;   // fold: 32B segments per (patch,row)
  }

#pragma unroll
  for (int off = 32; off >= 1; off >>= 1) pen += __shfl_xor(pen, off, 64);
  if (lane == 0) atomicAdd(penAcc, pen);
}

__global__ void finalize_kernel(float* penSlot) {
  *penSlot = 1.0f - (*penSlot) * (1.0f / (float)NPATCH);
}

extern "C" void kernel_launch(void* const* d_in, const int* in_sizes, int n_in,
                              void* d_out, int out_size, void* d_ws, size_t ws_size,
                              hipStream_t stream) {
  const float* img = (const float*)d_in[0];   // 16777216 fp32
  const float* blk = (const float*)d_in[1];   // 16384 fp32
  float* out = (float*)d_out;                 // 16777217 fp32
  float* penSlot = out + IMG_ELEMS;

  hipMemsetAsync(penSlot, 0, sizeof(float), stream);
  recon_kernel<<<dim3(4096), dim3(256), 0, stream>>>(img, blk, out, penSlot);
  finalize_kernel<<<dim3(1), dim3(1), 0, stream>>>(penSlot);
}

// Round 4
// 360.072 us; speedup vs baseline: 1.1290x; 1.1290x over previous
//
#include <hip/hip_runtime.h>
#include <hip/hip_fp16.h>

// ImageReconstruction: unfold -> soft-VQ softmax(35*(2ab - b2)) over 256 codes
// -> sparse reconstruct -> fold, + choice penalty (sum min(w,1-w) / N).
//
// GEMM1 via bf16 split-2 MFMA (the HW-verified mfma_f32_16x16x32_bf16):
//   a = ah + al (bf16 hi + bf16 residual; bf16 has full fp32 exponent range,
//   so no denormal hazard), ab = (Ah+Al)*(Bh+Bl): 8 mfmas per 16-code tile,
//   all same scale -> single accumulator. |dlogit| <= 70*64*2*2^-18 ~ 0.017
//   worst-case aligned, ~1e-3 realistic.
// B LDS layout: code-row stride 9 granules (36 words): b128 read bank-group
//   = (c15 + q + 4s) & 7 -> bijection per lane-octet -> conflict-free.
// Epilogue: dense W (bf16) in LDS, ballot/ctz sparse scan (beta=35 is
//   near-one-hot; tau=1e-6 drop error <= 2.6e-4), recon staged in LDS and
//   written out as coalesced float4 (round-1 counters showed 8x write amp
//   from scattered 32B fold stores: WRITE_SIZE 546MB for a 67MB output).

typedef short short8 __attribute__((ext_vector_type(8)));
typedef float floatx4 __attribute__((ext_vector_type(4)));

namespace {
constexpr float BETA_C = 35.0f;
constexpr float TAU    = 1e-6f;
constexpr float INV_N  = 1.0f / 262144.0f;
constexpr size_t IMG_ELEMS = (size_t)64 * 512 * 512;
// LDS word (uint32) map, total 13312 words = 53248 B -> 3 blocks/CU.
constexpr int WB   = 0;      // B half (Bh then Bl): [0, 9216)
constexpr int WA_H = 9216;   // A-hi staging: [9216, 11264)
constexpr int WA_L = 11264;  // A-lo staging: [11264, 13312)
constexpr int WW   = 0;      // W bf16 (reuse B): p*132 + k/2, [0, 8448)
constexpr int WR   = 8448;   // recon f32: p*68 + d, [8448, 12800)
constexpr int NWORDS = 13312;
}

__device__ __forceinline__ unsigned short f2bf(float x) {  // round-to-nearest
  unsigned u = __float_as_uint(x);
  return (unsigned short)((u + 0x7FFFu + ((u >> 16) & 1u)) >> 16);
}
__device__ __forceinline__ float bf2f(unsigned short h) {
  return __uint_as_float((unsigned)h << 16);
}
__device__ __forceinline__ unsigned pack2(unsigned short lo, unsigned short hi) {
  return (unsigned)lo | ((unsigned)hi << 16);
}

// Pre-kernel: split codebook into bf16 hi/lo granules (packed stride-8; the
// main kernel re-strides to 9 while staging) + per-code squared norms.
__global__ void pack_codes(const float* __restrict__ blk,
                           unsigned* __restrict__ wsBh,
                           unsigned* __restrict__ wsBl,
                           float* __restrict__ wsB2) {
  const int c = threadIdx.x;  // 256 threads, one code each
  const float* src = blk + c * 64;
  float b2 = 0.f;
#pragma unroll
  for (int g = 0; g < 8; ++g) {
#pragma unroll
    for (int t = 0; t < 4; ++t) {
      float v0 = src[g * 8 + 2 * t], v1 = src[g * 8 + 2 * t + 1];
      b2 += v0 * v0 + v1 * v1;
      unsigned short h0 = f2bf(v0), h1 = f2bf(v1);
      unsigned short l0 = f2bf(v0 - bf2f(h0)), l1 = f2bf(v1 - bf2f(h1));
      wsBh[(c * 8 + g) * 4 + t] = pack2(h0, h1);
      wsBl[(c * 8 + g) * 4 + t] = pack2(l0, l1);
    }
  }
  wsB2[c] = b2;
}

__global__ __launch_bounds__(256, 3) void recon_kernel(
    const float* __restrict__ img, const float* __restrict__ blk,
    const unsigned* __restrict__ wsBh, const unsigned* __restrict__ wsBl,
    const float* __restrict__ wsB2, float* __restrict__ out,
    float* __restrict__ penAcc) {
  __shared__ unsigned sMem[NWORDS];
  float* sMemF = reinterpret_cast<float*>(sMem);

  const int tid = threadIdx.x;
  const int lane = tid & 63;
  const int wave = tid >> 6;
  const int b = blockIdx.x >> 6;
  const int ht = blockIdx.x & 63;
  const int c15 = lane & 15;
  const int q = lane >> 4;

  // ---- stage Bh: packed granule j -> strided j + j/8 (16B units) ----
  {
    const uint4* src = reinterpret_cast<const uint4*>(wsBh);
#pragma unroll
    for (int i = 0; i < 8; ++i) {
      int j = i * 256 + tid;
      *reinterpret_cast<uint4*>(&sMem[WB + (j + (j >> 3)) * 4]) = src[j];
    }
  }
  // ---- stage A: bf16 hi/lo split, [patch][granule] stride 8 (no pad) ----
  const float* imgBase = img + (size_t)b * (512 * 512) + (size_t)(ht * 8) * 512;
#pragma unroll
  for (int i = 0; i < 4; ++i) {
    int f4 = i * 256 + tid;
    int row = f4 >> 7, c4 = f4 & 127;   // image row in tile, float4 col
    float4 v = reinterpret_cast<const float4*>(imgBase + row * 512)[c4];
    int wt = c4 >> 1, hw = c4 & 1;      // patch col-index, half-of-granule
    unsigned short h0 = f2bf(v.x), h1 = f2bf(v.y), h2 = f2bf(v.z), h3 = f2bf(v.w);
    unsigned short l0 = f2bf(v.x - bf2f(h0)), l1 = f2bf(v.y - bf2f(h1));
    unsigned short l2 = f2bf(v.z - bf2f(h2)), l3 = f2bf(v.w - bf2f(h3));
    int base = wt * 32 + row * 4 + hw * 2;   // granule g = row; d = row*8+kw
    *reinterpret_cast<uint2*>(&sMem[WA_H + base]) =
        make_uint2(pack2(h0, h1), pack2(h2, h3));
    *reinterpret_cast<uint2*>(&sMem[WA_L + base]) =
        make_uint2(pack2(l0, l1), pack2(l2, l3));
  }
  __syncthreads();  // bar1: A + Bh staged

  // ---- A fragments: lane(c15,q) holds A[m=c15][k=32s+8q+j] ----
  const int patch = wave * 16 + c15;
  short8 ah[2], al[2];
#pragma unroll
  for (int s = 0; s < 2; ++s) {
    int base = patch * 32 + (4 * s + q) * 4;
    ah[s] = *reinterpret_cast<const short8*>(&sMem[WA_H + base]);
    al[s] = *reinterpret_cast<const short8*>(&sMem[WA_L + base]);
  }

  floatx4 acc[16];
#pragma unroll
  for (int n = 0; n < 16; ++n) acc[n] = (floatx4){0.f, 0.f, 0.f, 0.f};

  // ---- phase 1: (Ah + Al) * Bh ----
#pragma unroll
  for (int n = 0; n < 16; ++n) {
    const unsigned* pb = &sMem[WB + (144 * n + 9 * c15 + q) * 4];
    short8 b0 = *reinterpret_cast<const short8*>(pb);        // k 8q..8q+7
    short8 b1 = *reinterpret_cast<const short8*>(pb + 16);   // k 32+8q..
    acc[n] = __builtin_amdgcn_mfma_f32_16x16x32_bf16(ah[0], b0, acc[n], 0, 0, 0);
    acc[n] = __builtin_amdgcn_mfma_f32_16x16x32_bf16(al[0], b0, acc[n], 0, 0, 0);
    acc[n] = __builtin_amdgcn_mfma_f32_16x16x32_bf16(ah[1], b1, acc[n], 0, 0, 0);
    acc[n] = __builtin_amdgcn_mfma_f32_16x16x32_bf16(al[1], b1, acc[n], 0, 0, 0);
  }
  __syncthreads();  // bar2: Bh reads done
  {
    const uint4* src = reinterpret_cast<const uint4*>(wsBl);
#pragma unroll
    for (int i = 0; i < 8; ++i) {
      int j = i * 256 + tid;
      *reinterpret_cast<uint4*>(&sMem[WB + (j + (j >> 3)) * 4]) = src[j];
    }
  }
  __syncthreads();  // bar3: Bl staged
  // ---- phase 2: (Ah + Al) * Bl ----
#pragma unroll
  for (int n = 0; n < 16; ++n) {
    const unsigned* pb = &sMem[WB + (144 * n + 9 * c15 + q) * 4];
    short8 b0 = *reinterpret_cast<const short8*>(pb);
    short8 b1 = *reinterpret_cast<const short8*>(pb + 16);
    acc[n] = __builtin_amdgcn_mfma_f32_16x16x32_bf16(ah[0], b0, acc[n], 0, 0, 0);
    acc[n] = __builtin_amdgcn_mfma_f32_16x16x32_bf16(al[0], b0, acc[n], 0, 0, 0);
    acc[n] = __builtin_amdgcn_mfma_f32_16x16x32_bf16(ah[1], b1, acc[n], 0, 0, 0);
    acc[n] = __builtin_amdgcn_mfma_f32_16x16x32_bf16(al[1], b1, acc[n], 0, 0, 0);
  }

  // ---- logits (C layout: col=c15 -> code 16n+c15, row=4q+r -> patch) ----
#pragma unroll
  for (int n = 0; n < 16; ++n) {
    float b2v = wsB2[16 * n + c15];
#pragma unroll
    for (int r = 0; r < 4; ++r)
      acc[n][r] = fmaf(2.0f * BETA_C, acc[n][r], -BETA_C * b2v);
  }
  // ---- softmax over 256 codes: reduce over n (reg) + c15 (xor 1..8) ----
  float mx[4], sm[4];
#pragma unroll
  for (int r = 0; r < 4; ++r) {
    float m = acc[0][r];
#pragma unroll
    for (int n = 1; n < 16; ++n) m = fmaxf(m, acc[n][r]);
#pragma unroll
    for (int off = 1; off <= 8; off <<= 1) m = fmaxf(m, __shfl_xor(m, off, 64));
    mx[r] = m;
    sm[r] = 0.f;
  }
#pragma unroll
  for (int n = 0; n < 16; ++n)
#pragma unroll
    for (int r = 0; r < 4; ++r) {
      acc[n][r] = __expf(acc[n][r] - mx[r]);
      sm[r] += acc[n][r];
    }
#pragma unroll
  for (int r = 0; r < 4; ++r) {
#pragma unroll
    for (int off = 1; off <= 8; off <<= 1) sm[r] += __shfl_xor(sm[r], off, 64);
    sm[r] = 1.0f / sm[r];
  }

  __syncthreads();  // bar4: all B reads done -> B region reusable as W

  // ---- penalty + dense W store (bf16, pair-packed -> 2-way-free b32) ----
  float pen = 0.f;
#pragma unroll
  for (int n = 0; n < 16; ++n)
#pragma unroll
    for (int r = 0; r < 4; ++r) {
      float w = acc[n][r] * sm[r];
      pen += fminf(w, 1.0f - w);
      float wp = __shfl_xor(w, 1, 64);   // partner code's weight
      if (!(c15 & 1)) {
        int p = wave * 16 + 4 * q + r;
        sMem[WW + p * 132 + 8 * n + (c15 >> 1)] = pack2(f2bf(w), f2bf(wp));
      }
    }
#pragma unroll
  for (int off = 1; off <= 32; off <<= 1) pen += __shfl_xor(pen, off, 64);
  if (lane == 0) atomicAdd(penAcc, pen);

  // ---- sparse scan (wave-local rows) + recon into LDS ----
#pragma unroll 1
  for (int pl = 0; pl < 16; ++pl) {
    int p = wave * 16 + pl;
    unsigned u0 = sMem[WW + p * 132 + lane];        // k = 2*lane, 2*lane+1
    unsigned u1 = sMem[WW + p * 132 + 64 + lane];   // k = 128+2*lane, +1
    float w0 = bf2f((unsigned short)(u0 & 0xFFFFu));
    float w1 = bf2f((unsigned short)(u0 >> 16));
    float w2 = bf2f((unsigned short)(u1 & 0xFFFFu));
    float w3 = bf2f((unsigned short)(u1 >> 16));
    bool flag = (w0 > TAU) || (w1 > TAU) || (w2 > TAU) || (w3 > TAU);
    unsigned long long msk = __ballot(flag);
    float rr = 0.f;
    while (msk) {                 // near-one-hot: typically 1-2 iterations
      int L = __builtin_ctzll(msk);
      msk &= msk - 1;
      unsigned a0 = (unsigned)__shfl((int)u0, L, 64);
      unsigned a1 = (unsigned)__shfl((int)u1, L, 64);
      float p0 = bf2f((unsigned short)(a0 & 0xFFFFu));
      float p1 = bf2f((unsigned short)(a0 >> 16));
      float p2 = bf2f((unsigned short)(a1 & 0xFFFFu));
      float p3 = bf2f((unsigned short)(a1 >> 16));
      const float* cb = blk + 2 * L * 64 + lane;    // L1/L2-hot, coalesced
      if (p0 > TAU) rr = fmaf(p0, cb[0], rr);
      if (p1 > TAU) rr = fmaf(p1, cb[64], rr);
      if (p2 > TAU) rr = fmaf(p2, cb[128 * 64], rr);
      if (p3 > TAU) rr = fmaf(p3, cb[128 * 64 + 64], rr);
    }
    sMemF[WR + p * 68 + lane] = rr;   // d = lane
  }
  __syncthreads();  // bar5: recon complete

  // ---- coalesced writeout of the block's 8x512 region ----
  float* outBase = out + (size_t)b * (512 * 512) + (size_t)(ht * 8) * 512;
#pragma unroll
  for (int i = 0; i < 4; ++i) {
    int f4 = i * 256 + tid;
    int row = f4 >> 7, c4 = f4 & 127;
    int wt = c4 >> 1, hw = c4 & 1;
    float4 v = *reinterpret_cast<const float4*>(
        &sMemF[WR + wt * 68 + row * 8 + hw * 4]);
    reinterpret_cast<float4*>(outBase + row * 512)[c4] = v;
  }
}

__global__ void finalize_kernel(float* penSlot) {
  *penSlot = (*penSlot) * INV_N;
}

extern "C" void kernel_launch(void* const* d_in, const int* in_sizes, int n_in,
                              void* d_out, int out_size, void* d_ws, size_t ws_size,
                              hipStream_t stream) {
  const float* img = (const float*)d_in[0];   // (64,1,512,512) fp32
  const float* blk = (const float*)d_in[1];   // (256,8,8) fp32
  float* out = (float*)d_out;
  float* penSlot = out + IMG_ELEMS;

  unsigned* wsBh = (unsigned*)d_ws;           // 32 KB
  unsigned* wsBl = wsBh + 8192;               // 32 KB
  float* wsB2 = (float*)(wsBl + 8192);        // 1 KB

  pack_codes<<<dim3(1), dim3(256), 0, stream>>>(blk, wsBh, wsBl, wsB2);
  hipMemsetAsync(penSlot, 0, sizeof(float), stream);
  recon_kernel<<<dim3(4096), dim3(256), 0, stream>>>(img, blk, wsBh, wsBl,
                                                     wsB2, out, penSlot);
  finalize_kernel<<<dim3(1), dim3(1), 0, stream>>>(penSlot);
}